// Round 3
// baseline (252.735 us; speedup 1.0000x reference)
//
#include <hip/hip_runtime.h>
#include <hip/hip_fp16.h>
#include <math.h>

#define NPG 54
#define EPG 144
#define GLOB 10
#define VROW 216   // V row: 216 embeds only (g fused into out_mlp)
#define GPB 2      // graphs (waves) per block in graph_kernel

typedef _Float16 f16x8 __attribute__((ext_vector_type(8)));
typedef _Float16 f16x4 __attribute__((ext_vector_type(4)));
typedef float    f32x4 __attribute__((ext_vector_type(4)));

// intra-wave LDS fence: all this wave's DS ops complete + compiler ordering.
// (waves in a block share no LDS region -> no s_barrier needed anywhere)
#define WSYNC() asm volatile("s_waitcnt lgkmcnt(0)" ::: "memory")

// ---------------------------------------------------------------------------
// Kernel 1: one WAVE per graph, operand-SWAPPED dataflow (everything computed
// transposed, C col = node) using ONLY round-0-proven constructs:
// mfma_f32_16x16x32_f16, plain LDS loads/stores, ds_pk_add_f16 atomics.
//   conv1: agg1^T = X^T @ Adj^T   (A=X^T from global, B=round-0 Adj b128 frags)
//   lin1 : h1^T   = Wc1^T @ cat^T (wf1 regs as A); h1 -> cat[16..31] packed
//                                  + H1T transposed copy (16 scalar b16 stores)
//   conv2: agg2^T = H1T @ Adj^T   (A=H1T b128 rows, B=same Adj frags)
//   lin2 : h2^T   = Wc2^T @ cat^T -> direct packed global V store (no LDS)
// DS ops/wave ~59 (round 0: ~109, incl. 64 scalar transpose stores).
// LDS per graph = 8864 B -> 17728 B/block -> 9 blocks/CU (same as round 0).
// ---------------------------------------------------------------------------
struct __align__(16) GL {
    _Float16 Adj[NPG][56];  // 6048 B; after af snapshot, overlaid by cat[64][40]
                            //   cat cols: 0..7 agg1 / 8..15 x  (lin1 K=32)
                            //             0..15 agg2 / 16..31 h1 (lin2 K=32)
    _Float16 H1T[16][88];   // 2816 B: h1^T [feat][node], stride 88 halves:
                            //   b128 row reads 2-way-free, scalar col stores 4-way
};

__global__ __launch_bounds__(128, 5) void graph_kernel(
    const float* __restrict__ x,
    const int*   __restrict__ edge_index,
    const float* __restrict__ edge_attr,
    const float* __restrict__ W_rel1, const float* __restrict__ b1,
    const float* __restrict__ W_root1,
    const float* __restrict__ W_rel2, const float* __restrict__ b2,
    const float* __restrict__ W_root2,
    _Float16* __restrict__ v_out,     // [B, VROW] fp16
    int E_total)
{
    __shared__ GL S[GPB];
    const int tid  = threadIdx.x;
    const int w    = tid >> 6;
    const int lane = tid & 63;
    const int ln15 = lane & 15;
    const int quad = lane >> 4;
    const int g    = blockIdx.x * GPB + w;
    GL& L = S[w];
    const int nbase = g * NPG;
    const int ebase = g * EPG;

    _Float16* adjp = &L.Adj[0][0];
    _Float16 (*cat)[40] = (_Float16(*)[40])adjp;   // overlay (rows 0..63, 5120 B)

    // ---- issue global loads FIRST (stay in flight through zeroing) ----
    int   esrc_r[3], edst_r[3];
    float ea_r[3];
    #pragma unroll
    for (int k = 0; k < 3; k++) {
        int e = lane + 64 * k;
        if (e < EPG) {
            esrc_r[k] = edge_index[ebase + e] - nbase;
            edst_r[k] = edge_index[(size_t)E_total + ebase + e] - nbase;
            ea_r[k]   = edge_attr[ebase + e];
        } else { esrc_r[k] = 0; edst_r[k] = -1; ea_r[k] = 0.0f; }
    }
    // X^T A-fragments for 16x16x32: xA[c][m] = x[src = c*32+quad*8+m][feat = ln15],
    // zero beyond 54 nodes / 8 feats (guards also keep Adj col-spill products zero).
    f16x8 xA[2];
    #pragma unroll
    for (int c = 0; c < 2; c++) {
        #pragma unroll
        for (int m = 0; m < 8; m++) {
            int src = c * 32 + quad * 8 + m;
            float v = 0.0f;
            if (ln15 < 8 && src < NPG) v = x[(size_t)(nbase + src) * 8 + ln15];
            xA[c][m] = (_Float16)v;
        }
    }
    // coalesced x row copy for the root path (cat cols 8..15)
    f16x8 xv = {0, 0, 0, 0, 0, 0, 0, 0};
    if (lane < NPG) {
        const float4* xg4 = (const float4*)(x + (size_t)(nbase + lane) * 8);
        float4 lo = xg4[0], hi = xg4[1];
        xv = (f16x8){ (_Float16)lo.x, (_Float16)lo.y, (_Float16)lo.z, (_Float16)lo.w,
                      (_Float16)hi.x, (_Float16)hi.y, (_Float16)hi.z, (_Float16)hi.w };
    }

    // ---- weight A-fragments in registers (A row = out-feature = ln15) ----
    // wf1[m] = Wcat1[k = quad*8+m][ln15]; k 0..7 = W_rel1, 8..15 = W_root1, rest 0
    f16x8 wf1 = {0, 0, 0, 0, 0, 0, 0, 0};
    if (quad == 0) {
        #pragma unroll
        for (int j = 0; j < 8; j++) wf1[j] = (_Float16)W_rel1[j * 16 + ln15];
    } else if (quad == 1) {
        #pragma unroll
        for (int j = 0; j < 8; j++) wf1[j] = (_Float16)W_root1[j * 16 + ln15];
    }
    // wf2[m] = Wcat2[k = quad*8+m][ln15], valid out < 4; k<16 W_rel2, else W_root2
    f16x8 wf2 = {0, 0, 0, 0, 0, 0, 0, 0};
    if (ln15 < 4) {
        #pragma unroll
        for (int j = 0; j < 8; j++) {
            int k = quad * 8 + j;
            wf2[j] = (_Float16)((k < 16) ? W_rel2[k * 4 + ln15]
                                         : W_root2[(k - 16) * 4 + ln15]);
        }
    }
    // biases: output-feature index is C row = quad*4 + r
    const float4 b1q = *(const float4*)(b1 + quad * 4);
    const float4 b2q = *(const float4*)b2;

    // ---- zero the whole per-graph region (8864 B = 554 uint4) ----
    {
        uint4* z = (uint4*)&L;
        for (int i = lane; i < 554; i += 64) z[i] = make_uint4(0, 0, 0, 0);
    }
    WSYNC();   // zeros visible before atomics

    // ---- build Adj directly: one ds_pk_add_f16 per edge (dups sum in HW) ----
    #pragma unroll
    for (int k = 0; k < 3; k++) {
        if (edst_r[k] >= 0) {
            int s = esrc_r[k];
            __half2* cell = (__half2*)&L.Adj[edst_r[k]][s & ~1];
            __half a16 = __float2half(ea_r[k]);
            __half z16 = __float2half(0.0f);
            __half2 val = (s & 1) ? __halves2half2(z16, a16)
                                  : __halves2half2(a16, z16);
            unsafeAtomicAdd(cell, val);
        }
    }
    WSYNC();

    // ---- Adj^T B-fragments -> regs (round-0 layout), reused by BOTH convs.
    //      af[t][c][m] = Adj[dst = t*16+ln15][src = c*32+quad*8+m].
    //      Row/col spills (>=54) hit zeroed LDS or pair with zero A cols. ----
    f16x8 af[4][2];
    #pragma unroll
    for (int t = 0; t < 4; t++)
        #pragma unroll
        for (int c = 0; c < 2; c++)
            af[t][c] = *(const f16x8*)(adjp + (t * 16 + ln15) * 56 + c * 32 + quad * 8);
    WSYNC();   // af snapshot in regs before cat overlay writes

    // ---- conv1: agg1^T = X^T @ Adj^T (C: col=node=t*16+ln15, row=feat=quad*4+r) ----
    f32x4 acc1[4];
    #pragma unroll
    for (int t = 0; t < 4; t++) acc1[t] = (f32x4){0.f, 0.f, 0.f, 0.f};
    #pragma unroll
    for (int c = 0; c < 2; c++)
        #pragma unroll
        for (int t = 0; t < 4; t++)
            acc1[t] = __builtin_amdgcn_mfma_f32_16x16x32_f16(xA[c], af[t][c], acc1[t], 0, 0, 0);
    // packed stores: agg1 feats 0..7 live in quads 0,1 -> cat[node][quad*4..+3]
    // (quads 2,3 are structural zeros and MUST NOT store: cols 8..15 belong to xv)
    if (quad < 2) {
        #pragma unroll
        for (int t = 0; t < 4; t++) {
            f16x4 ap;
            #pragma unroll
            for (int r = 0; r < 4; r++) ap[r] = (_Float16)acc1[t][r];
            *(f16x4*)&cat[t * 16 + ln15][quad * 4] = ap;
        }
    }
    if (lane < NPG) *(f16x8*)&cat[lane][8] = xv;   // root features, cols 8..15
    WSYNC();

    // ---- lin1: h1^T = Wc1^T @ cat^T + b1, relu.
    //      Store h1 twice: packed to cat[node][16+quad*4] (lin2 B operand),
    //      and transposed to H1T[feat][node] (conv2 A operand, 16 scalar b16). ----
    f32x4 ci1 = {b1q.x, b1q.y, b1q.z, b1q.w};
    #pragma unroll
    for (int t = 0; t < 4; t++) {
        f16x8 bc = *(const f16x8*)&cat[t * 16 + ln15][quad * 8];  // k 16..31: garbage x wf1=0
        f32x4 hL = __builtin_amdgcn_mfma_f32_16x16x32_f16(wf1, bc, ci1, 0, 0, 0);
        int node = t * 16 + ln15;
        f16x4 hp;
        #pragma unroll
        for (int r = 0; r < 4; r++) hp[r] = (_Float16)fmaxf(hL[r], 0.0f);
        *(f16x4*)&cat[node][16 + quad * 4] = hp;         // rows >=54 garbage, guarded later
        if (node < NPG) {                                 // H1T cols 54..87 stay ZERO
            #pragma unroll
            for (int r = 0; r < 4; r++) L.H1T[quad * 4 + r][node] = hp[r];
        }
    }
    WSYNC();

    // ---- conv2: agg2^T = H1T @ Adj^T; A-frags are packed H1T row reads ----
    f16x8 hA[2];
    #pragma unroll
    for (int c = 0; c < 2; c++)
        hA[c] = *(const f16x8*)&L.H1T[ln15][c * 32 + quad * 8];
    f32x4 acc2[4];
    #pragma unroll
    for (int t = 0; t < 4; t++) acc2[t] = (f32x4){0.f, 0.f, 0.f, 0.f};
    #pragma unroll
    for (int c = 0; c < 2; c++)
        #pragma unroll
        for (int t = 0; t < 4; t++)
            acc2[t] = __builtin_amdgcn_mfma_f32_16x16x32_f16(hA[c], af[t][c], acc2[t], 0, 0, 0);
    // agg2 feats 0..15 -> cat cols 0..15 (agg1/xv dead); h1 in 16..31 untouched
    #pragma unroll
    for (int t = 0; t < 4; t++) {
        f16x4 ap;
        #pragma unroll
        for (int r = 0; r < 4; r++) ap[r] = (_Float16)acc2[t][r];
        *(f16x4*)&cat[t * 16 + ln15][quad * 4] = ap;
    }
    WSYNC();

    // ---- lin2: h2^T = Wc2^T @ [agg2|h1]^T + b2, relu; direct global V store ----
    f32x4 ci2 = {b2q.x, b2q.y, b2q.z, b2q.w};
    #pragma unroll
    for (int t = 0; t < 4; t++) {
        int node = t * 16 + ln15;
        f16x8 bv = *(const f16x8*)&cat[node][quad * 8];
        f32x4 o = __builtin_amdgcn_mfma_f32_16x16x32_f16(wf2, bv, ci2, 0, 0, 0);
        if (quad == 0 && node < NPG) {     // real outputs = rows 0..3 = quad 0
            f16x4 vp;
            #pragma unroll
            for (int r = 0; r < 4; r++) vp[r] = (_Float16)fmaxf(o[r], 0.0f);
            *(f16x4*)(v_out + (size_t)g * VROW + node * 4) = vp;
        }
    }
}

// ---------------------------------------------------------------------------
// Kernel 2: out-MLP via fp16 MFMA (unchanged: LDS Bt staging, 512 threads),
// with the 10->8->8->10 global MLP fused per-lane in fp32.
// ---------------------------------------------------------------------------
#define BTS 264

__global__ __launch_bounds__(512) void out_mlp_mfma(
    const _Float16* __restrict__ V,    // [B, VROW] fp16
    const float* __restrict__ gf,      // [B, 10]
    const float* __restrict__ Wg1, const float* __restrict__ bg1,
    const float* __restrict__ Wg2, const float* __restrict__ bg2,
    const float* __restrict__ Wg3, const float* __restrict__ bg3,
    const float* __restrict__ Wo1,     // [226, 128] fp32
    const float* __restrict__ bo1,
    const float* __restrict__ Wo2,
    const float* __restrict__ bo2,
    float* __restrict__ out)
{
    extern __shared__ _Float16 Bt[];   // [128][BTS] = 67584 B

    const int tid  = threadIdx.x;
    const int w    = tid >> 6;
    const int lane = tid & 63;
    const int ln15 = lane & 15;
    const int quad = lane >> 4;
    const int row0 = blockIdx.x * 128;
    const int row  = row0 + w * 16 + ln15;

    float bo1v[8], wo2v[8];
    #pragma unroll
    for (int t = 0; t < 8; t++) {
        bo1v[t] = bo1[t * 16 + ln15];
        wo2v[t] = Wo2[t * 16 + ln15];
    }
    const float bo2v = bo2[0];

    // ---- per-lane global-MLP for this lane's row (fp32) ----
    float t3[GLOB];
    {
        const float* gr = gf + (size_t)row * GLOB;
        float t0[GLOB];
        #pragma unroll
        for (int i = 0; i < GLOB; i++) t0[i] = gr[i];
        float t1[8];
        #pragma unroll
        for (int j = 0; j < 8; j++) {
            float a = bg1[j];
            #pragma unroll
            for (int i = 0; i < GLOB; i++) a += t0[i] * Wg1[i * 8 + j];
            t1[j] = fmaxf(a, 0.0f);
        }
        float t2[8];
        #pragma unroll
        for (int j = 0; j < 8; j++) {
            float a = bg2[j];
            #pragma unroll
            for (int i = 0; i < 8; i++) a += t1[i] * Wg2[i * 8 + j];
            t2[j] = fmaxf(a, 0.0f);
        }
        #pragma unroll
        for (int j = 0; j < GLOB; j++) {
            float a = bg3[j];
            #pragma unroll
            for (int i = 0; i < 8; i++) a += t2[i] * Wg3[i * GLOB + j];
            t3[j] = fmaxf(a, 0.0f);
        }
    }

    // ---- A-fragments: s<6 from V; s=6 quad3 + s=7 quad0 from g ----
    const _Float16* Arow = V + (size_t)row * VROW;
    f16x8 af[8];
    #pragma unroll
    for (int s = 0; s < 6; s++)
        af[s] = *(const f16x8*)(Arow + s * 32 + quad * 8);
    if (quad == 3)
        af[6] = (f16x8){ (_Float16)t3[0], (_Float16)t3[1], (_Float16)t3[2], (_Float16)t3[3],
                         (_Float16)t3[4], (_Float16)t3[5], (_Float16)t3[6], (_Float16)t3[7] };
    else
        af[6] = *(const f16x8*)(Arow + 192 + quad * 8);
    af[7] = (f16x8){0, 0, 0, 0, 0, 0, 0, 0};
    if (quad == 0) { af[7][0] = (_Float16)t3[8]; af[7][1] = (_Float16)t3[9]; }

    // ---- zero Bt, then stage Wo1 transposed fp16 ----
    {
        int4* bz = (int4*)Bt;
        for (int i = tid; i < 4224; i += 512)
            bz[i] = make_int4(0, 0, 0, 0);
    }
    __syncthreads();
    for (int i = tid; i < 7232; i += 512) {
        int k  = i >> 5;
        int nq = (i & 31) * 4;
        float4 v = *(const float4*)(Wo1 + (size_t)k * 128 + nq);
        Bt[(nq + 0) * BTS + k] = (_Float16)v.x;
        Bt[(nq + 1) * BTS + k] = (_Float16)v.y;
        Bt[(nq + 2) * BTS + k] = (_Float16)v.z;
        Bt[(nq + 3) * BTS + k] = (_Float16)v.w;
    }
    __syncthreads();

    f32x4 acc[8];
    #pragma unroll
    for (int t = 0; t < 8; t++) acc[t] = (f32x4){0.f, 0.f, 0.f, 0.f};

    for (int s = 0; s < 8; s++) {
        #pragma unroll
        for (int t = 0; t < 8; t++) {
            f16x8 bf = *(const f16x8*)&Bt[(t * 16 + ln15) * BTS + s * 32 + quad * 8];
            acc[t] = __builtin_amdgcn_mfma_f32_16x16x32_f16(af[s], bf, acc[t], 0, 0, 0);
        }
    }

    #pragma unroll
    for (int rr = 0; rr < 4; rr++) {
        float p = 0.0f;
        #pragma unroll
        for (int t = 0; t < 8; t++) {
            float h = fmaxf(acc[t][rr] + bo1v[t], 0.0f);
            p += h * wo2v[t];
        }
        p += __shfl_xor(p, 1);
        p += __shfl_xor(p, 2);
        p += __shfl_xor(p, 4);
        p += __shfl_xor(p, 8);
        if (ln15 == rr) {
            int orow = row0 + w * 16 + quad * 4 + rr;
            out[orow] = 1.0f / (1.0f + expf(-(p + bo2v)));
        }
    }
}

// ---------------------------------------------------------------------------
extern "C" void kernel_launch(void* const* d_in, const int* in_sizes, int n_in,
                              void* d_out, int out_size, void* d_ws, size_t ws_size,
                              hipStream_t stream) {
    const float* x        = (const float*)d_in[0];
    const int*   ei       = (const int*)  d_in[1];
    const float* ea       = (const float*)d_in[2];
    const float* gf       = (const float*)d_in[3];
    const float* W_rel1   = (const float*)d_in[4];
    const float* b1       = (const float*)d_in[5];
    const float* W_root1  = (const float*)d_in[6];
    const float* W_rel2   = (const float*)d_in[7];
    const float* b2       = (const float*)d_in[8];
    const float* W_root2  = (const float*)d_in[9];
    const float* Wg1      = (const float*)d_in[10];
    const float* bg1      = (const float*)d_in[11];
    const float* Wg2      = (const float*)d_in[12];
    const float* bg2      = (const float*)d_in[13];
    const float* Wg3      = (const float*)d_in[14];
    const float* bg3      = (const float*)d_in[15];
    const float* Wo1      = (const float*)d_in[16];
    const float* bo1      = (const float*)d_in[17];
    const float* Wo2      = (const float*)d_in[18];
    const float* bo2      = (const float*)d_in[19];

    float* out   = (float*)d_out;
    _Float16* V  = (_Float16*)d_ws;             // [B, VROW] fp16

    const int B = out_size;                     // 32768
    const int E = in_sizes[1] / 2;

    graph_kernel<<<B / GPB, 128, 0, stream>>>(
        x, ei, ea,
        W_rel1, b1, W_root1, W_rel2, b2, W_root2,
        V, E);

    out_mlp_mfma<<<B / 128, 512, 128 * BTS * sizeof(_Float16), stream>>>(
        V, gf, Wg1, bg1, Wg2, bg2, Wg3, bg3, Wo1, bo1, Wo2, bo2, out);
}

// Round 4
// 208.475 us; speedup vs baseline: 1.2123x; 1.2123x over previous
//
#include <hip/hip_runtime.h>
#include <hip/hip_fp16.h>
#include <math.h>

#define NPG 54
#define EPG 144
#define GLOB 10
#define VROW 216   // V row: 216 embeds only (g fused into out_mlp)
#define GPB 2      // graphs (waves) per block in graph_kernel

typedef _Float16 f16x8 __attribute__((ext_vector_type(8)));
typedef _Float16 f16x4 __attribute__((ext_vector_type(4)));
typedef float    f32x4 __attribute__((ext_vector_type(4)));

// intra-wave LDS fence: all this wave's DS ops complete + compiler ordering.
// (waves in a block share no LDS region -> no s_barrier needed anywhere)
#define WSYNC() asm volatile("s_waitcnt lgkmcnt(0)" ::: "memory")

// ---------------------------------------------------------------------------
// Kernel 1: one WAVE per graph, operand-SWAPPED dataflow (everything computed
// transposed, C col = node). Round-4 change vs round 3: the conv1 A-operand
// X^T comes from LDS (staged from the coalesced xv row load), NOT from a
// 16-instruction guarded global gather -- that gather serialized ~10k cy/wave
// of VMEM latency under VGPR pressure and caused the 69->108 us regression.
//   conv1: agg1^T = X^T @ Adj^T   (A=XT LDS b128 reads, B=Adj b128 frags)
//   lin1 : h1^T   = Wc1^T @ cat^T (wf1 regs as A); h1 -> cat[16..31] packed
//                                  + H1T transposed copy (overwrites XT)
//   conv2: agg2^T = H1T @ Adj^T   (A=H1T b128 rows, B=same Adj frags)
//   lin2 : h2^T   = Wc2^T @ cat^T -> direct packed global V store (no LDS)
// DS ops/wave ~69 (round 0: ~109). Only global ops are round-0-proven ones.
// LDS per graph = 8864 B -> 17728 B/block -> 9 blocks/CU = 18 waves.
// ---------------------------------------------------------------------------
struct __align__(16) GL {
    _Float16 Adj[NPG][56];  // 6048 B; after af snapshot, overlaid by cat[64][40]
                            //   cat cols: 0..7 agg1 / 8..15 x  (lin1 K=32)
                            //             0..15 agg2 / 16..31 h1 (lin2 K=32)
    _Float16 H1T[16][88];   // 2816 B, stride 88 halves (176 B, 16B-aligned rows):
                            //   phase 1: XT[feat][node] = x^T   (conv1 A reads)
                            //   phase 2: h1^T[feat][node]       (conv2 A reads)
                            //   cols 54..87 stay zero throughout
};

__global__ __launch_bounds__(128, 5) void graph_kernel(
    const float* __restrict__ x,
    const int*   __restrict__ edge_index,
    const float* __restrict__ edge_attr,
    const float* __restrict__ W_rel1, const float* __restrict__ b1,
    const float* __restrict__ W_root1,
    const float* __restrict__ W_rel2, const float* __restrict__ b2,
    const float* __restrict__ W_root2,
    _Float16* __restrict__ v_out,     // [B, VROW] fp16
    int E_total)
{
    __shared__ GL S[GPB];
    const int tid  = threadIdx.x;
    const int w    = tid >> 6;
    const int lane = tid & 63;
    const int ln15 = lane & 15;
    const int quad = lane >> 4;
    const int g    = blockIdx.x * GPB + w;
    GL& L = S[w];
    const int nbase = g * NPG;
    const int ebase = g * EPG;

    _Float16* adjp = &L.Adj[0][0];
    _Float16 (*cat)[40] = (_Float16(*)[40])adjp;   // overlay (rows 0..63, 5120 B)

    // ---- issue global loads FIRST (stay in flight through zeroing) ----
    int   esrc_r[3], edst_r[3];
    float ea_r[3];
    #pragma unroll
    for (int k = 0; k < 3; k++) {
        int e = lane + 64 * k;
        if (e < EPG) {
            esrc_r[k] = edge_index[ebase + e] - nbase;
            edst_r[k] = edge_index[(size_t)E_total + ebase + e] - nbase;
            ea_r[k]   = edge_attr[ebase + e];
        } else { esrc_r[k] = 0; edst_r[k] = -1; ea_r[k] = 0.0f; }
    }
    // coalesced x row load: lane -> node, 2 x float4 (the ONLY x read)
    f16x8 xv = {0, 0, 0, 0, 0, 0, 0, 0};
    if (lane < NPG) {
        const float4* xg4 = (const float4*)(x + (size_t)(nbase + lane) * 8);
        float4 lo = xg4[0], hi = xg4[1];
        xv = (f16x8){ (_Float16)lo.x, (_Float16)lo.y, (_Float16)lo.z, (_Float16)lo.w,
                      (_Float16)hi.x, (_Float16)hi.y, (_Float16)hi.z, (_Float16)hi.w };
    }

    // ---- weight A-fragments in registers (A row = out-feature = ln15) ----
    // wf1[m] = Wcat1[k = quad*8+m][ln15]; k 0..7 = W_rel1, 8..15 = W_root1, rest 0
    f16x8 wf1 = {0, 0, 0, 0, 0, 0, 0, 0};
    if (quad == 0) {
        #pragma unroll
        for (int j = 0; j < 8; j++) wf1[j] = (_Float16)W_rel1[j * 16 + ln15];
    } else if (quad == 1) {
        #pragma unroll
        for (int j = 0; j < 8; j++) wf1[j] = (_Float16)W_root1[j * 16 + ln15];
    }
    // wf2[m] = Wcat2[k = quad*8+m][ln15], valid out < 4; k<16 W_rel2, else W_root2
    f16x8 wf2 = {0, 0, 0, 0, 0, 0, 0, 0};
    if (ln15 < 4) {
        #pragma unroll
        for (int j = 0; j < 8; j++) {
            int k = quad * 8 + j;
            wf2[j] = (_Float16)((k < 16) ? W_rel2[k * 4 + ln15]
                                         : W_root2[(k - 16) * 4 + ln15]);
        }
    }
    // biases: output-feature index is C row = quad*4 + r
    const float4 b1q = *(const float4*)(b1 + quad * 4);
    const float4 b2q = *(const float4*)b2;

    // ---- zero the whole per-graph region (8864 B = 554 uint4) ----
    {
        uint4* z = (uint4*)&L;
        for (int i = lane; i < 554; i += 64) z[i] = make_uint4(0, 0, 0, 0);
    }
    WSYNC();   // zeros visible before atomics / XT stores

    // ---- XT staging (into H1T region, disjoint from Adj): XT[feat][node].
    //      8 scalar b16 stores, 54 consecutive cols -> <=2 lanes/bank (free). ----
    if (lane < NPG) {
        #pragma unroll
        for (int f = 0; f < 8; f++) L.H1T[f][lane] = xv[f];
    }
    // ---- build Adj directly: one ds_pk_add_f16 per edge (dups sum in HW) ----
    #pragma unroll
    for (int k = 0; k < 3; k++) {
        if (edst_r[k] >= 0) {
            int s = esrc_r[k];
            __half2* cell = (__half2*)&L.Adj[edst_r[k]][s & ~1];
            __half a16 = __float2half(ea_r[k]);
            __half z16 = __float2half(0.0f);
            __half2 val = (s & 1) ? __halves2half2(z16, a16)
                                  : __halves2half2(a16, z16);
            unsafeAtomicAdd(cell, val);
        }
    }
    WSYNC();

    // ---- Adj^T B-fragments -> regs, reused by BOTH convs.
    //      af[t][c][m] = Adj[dst = t*16+ln15][src = c*32+quad*8+m].
    //      Row/col spills (>=54) hit zeroed LDS or pair with zero A cols. ----
    f16x8 af[4][2];
    #pragma unroll
    for (int t = 0; t < 4; t++)
        #pragma unroll
        for (int c = 0; c < 2; c++)
            af[t][c] = *(const f16x8*)(adjp + (t * 16 + ln15) * 56 + c * 32 + quad * 8);
    // ---- X^T A-fragments from XT: xA[c][m] = x[src = c*32+quad*8+m][ln15].
    //      Rows 8..15 (ln15 >= 8) and cols >= 54 are zero -> clean zeros. ----
    f16x8 xA[2];
    #pragma unroll
    for (int c = 0; c < 2; c++)
        xA[c] = *(const f16x8*)&L.H1T[ln15][c * 32 + quad * 8];
    WSYNC();   // af+xA snapshot in regs before cat overlay / H1T overwrite

    // ---- conv1: agg1^T = X^T @ Adj^T (C: col=node=t*16+ln15, row=feat=quad*4+r) ----
    f32x4 acc1[4];
    #pragma unroll
    for (int t = 0; t < 4; t++) acc1[t] = (f32x4){0.f, 0.f, 0.f, 0.f};
    #pragma unroll
    for (int c = 0; c < 2; c++)
        #pragma unroll
        for (int t = 0; t < 4; t++)
            acc1[t] = __builtin_amdgcn_mfma_f32_16x16x32_f16(xA[c], af[t][c], acc1[t], 0, 0, 0);
    // packed stores: agg1 feats 0..7 live in quads 0,1 -> cat[node][quad*4..+3]
    // (quads 2,3 are structural zeros and MUST NOT store: cols 8..15 belong to xv)
    if (quad < 2) {
        #pragma unroll
        for (int t = 0; t < 4; t++) {
            f16x4 ap;
            #pragma unroll
            for (int r = 0; r < 4; r++) ap[r] = (_Float16)acc1[t][r];
            *(f16x4*)&cat[t * 16 + ln15][quad * 4] = ap;
        }
    }
    if (lane < NPG) *(f16x8*)&cat[lane][8] = xv;   // root features, cols 8..15
    WSYNC();

    // ---- lin1: h1^T = Wc1^T @ cat^T + b1, relu.
    //      Store h1 twice: packed to cat[node][16+quad*4] (lin2 B operand),
    //      and transposed to H1T[feat][node] (conv2 A operand; overwrites XT:
    //      every (row 0..15, col<54) cell is rewritten, cols>=54 stay zero). ----
    f32x4 ci1 = {b1q.x, b1q.y, b1q.z, b1q.w};
    #pragma unroll
    for (int t = 0; t < 4; t++) {
        f16x8 bc = *(const f16x8*)&cat[t * 16 + ln15][quad * 8];  // k 16..31: garbage x wf1=0
        f32x4 hL = __builtin_amdgcn_mfma_f32_16x16x32_f16(wf1, bc, ci1, 0, 0, 0);
        int node = t * 16 + ln15;
        f16x4 hp;
        #pragma unroll
        for (int r = 0; r < 4; r++) hp[r] = (_Float16)fmaxf(hL[r], 0.0f);
        *(f16x4*)&cat[node][16 + quad * 4] = hp;         // rows >=54 nonzero, guarded later
        if (node < NPG) {                                 // H1T cols 54..87 stay ZERO
            #pragma unroll
            for (int r = 0; r < 4; r++) L.H1T[quad * 4 + r][node] = hp[r];
        }
    }
    WSYNC();

    // ---- conv2: agg2^T = H1T @ Adj^T; A-frags are packed H1T row reads ----
    f16x8 hA[2];
    #pragma unroll
    for (int c = 0; c < 2; c++)
        hA[c] = *(const f16x8*)&L.H1T[ln15][c * 32 + quad * 8];
    f32x4 acc2[4];
    #pragma unroll
    for (int t = 0; t < 4; t++) acc2[t] = (f32x4){0.f, 0.f, 0.f, 0.f};
    #pragma unroll
    for (int c = 0; c < 2; c++)
        #pragma unroll
        for (int t = 0; t < 4; t++)
            acc2[t] = __builtin_amdgcn_mfma_f32_16x16x32_f16(hA[c], af[t][c], acc2[t], 0, 0, 0);
    // agg2 feats 0..15 -> cat cols 0..15 (agg1/xv dead); h1 in 16..31 untouched
    #pragma unroll
    for (int t = 0; t < 4; t++) {
        f16x4 ap;
        #pragma unroll
        for (int r = 0; r < 4; r++) ap[r] = (_Float16)acc2[t][r];
        *(f16x4*)&cat[t * 16 + ln15][quad * 4] = ap;
    }
    WSYNC();

    // ---- lin2: h2^T = Wc2^T @ [agg2|h1]^T + b2, relu; direct global V store ----
    f32x4 ci2 = {b2q.x, b2q.y, b2q.z, b2q.w};
    #pragma unroll
    for (int t = 0; t < 4; t++) {
        int node = t * 16 + ln15;
        f16x8 bv = *(const f16x8*)&cat[node][quad * 8];
        f32x4 o = __builtin_amdgcn_mfma_f32_16x16x32_f16(wf2, bv, ci2, 0, 0, 0);
        if (quad == 0 && node < NPG) {     // real outputs = rows 0..3 = quad 0
            f16x4 vp;
            #pragma unroll
            for (int r = 0; r < 4; r++) vp[r] = (_Float16)fmaxf(o[r], 0.0f);
            *(f16x4*)(v_out + (size_t)g * VROW + node * 4) = vp;
        }
    }
}

// ---------------------------------------------------------------------------
// Kernel 2: out-MLP via fp16 MFMA (unchanged: LDS Bt staging, 512 threads),
// with the 10->8->8->10 global MLP fused per-lane in fp32.
// ---------------------------------------------------------------------------
#define BTS 264

__global__ __launch_bounds__(512) void out_mlp_mfma(
    const _Float16* __restrict__ V,    // [B, VROW] fp16
    const float* __restrict__ gf,      // [B, 10]
    const float* __restrict__ Wg1, const float* __restrict__ bg1,
    const float* __restrict__ Wg2, const float* __restrict__ bg2,
    const float* __restrict__ Wg3, const float* __restrict__ bg3,
    const float* __restrict__ Wo1,     // [226, 128] fp32
    const float* __restrict__ bo1,
    const float* __restrict__ Wo2,
    const float* __restrict__ bo2,
    float* __restrict__ out)
{
    extern __shared__ _Float16 Bt[];   // [128][BTS] = 67584 B

    const int tid  = threadIdx.x;
    const int w    = tid >> 6;
    const int lane = tid & 63;
    const int ln15 = lane & 15;
    const int quad = lane >> 4;
    const int row0 = blockIdx.x * 128;
    const int row  = row0 + w * 16 + ln15;

    float bo1v[8], wo2v[8];
    #pragma unroll
    for (int t = 0; t < 8; t++) {
        bo1v[t] = bo1[t * 16 + ln15];
        wo2v[t] = Wo2[t * 16 + ln15];
    }
    const float bo2v = bo2[0];

    // ---- per-lane global-MLP for this lane's row (fp32) ----
    float t3[GLOB];
    {
        const float* gr = gf + (size_t)row * GLOB;
        float t0[GLOB];
        #pragma unroll
        for (int i = 0; i < GLOB; i++) t0[i] = gr[i];
        float t1[8];
        #pragma unroll
        for (int j = 0; j < 8; j++) {
            float a = bg1[j];
            #pragma unroll
            for (int i = 0; i < GLOB; i++) a += t0[i] * Wg1[i * 8 + j];
            t1[j] = fmaxf(a, 0.0f);
        }
        float t2[8];
        #pragma unroll
        for (int j = 0; j < 8; j++) {
            float a = bg2[j];
            #pragma unroll
            for (int i = 0; i < 8; i++) a += t1[i] * Wg2[i * 8 + j];
            t2[j] = fmaxf(a, 0.0f);
        }
        #pragma unroll
        for (int j = 0; j < GLOB; j++) {
            float a = bg3[j];
            #pragma unroll
            for (int i = 0; i < 8; i++) a += t2[i] * Wg3[i * GLOB + j];
            t3[j] = fmaxf(a, 0.0f);
        }
    }

    // ---- A-fragments: s<6 from V; s=6 quad3 + s=7 quad0 from g ----
    const _Float16* Arow = V + (size_t)row * VROW;
    f16x8 af[8];
    #pragma unroll
    for (int s = 0; s < 6; s++)
        af[s] = *(const f16x8*)(Arow + s * 32 + quad * 8);
    if (quad == 3)
        af[6] = (f16x8){ (_Float16)t3[0], (_Float16)t3[1], (_Float16)t3[2], (_Float16)t3[3],
                         (_Float16)t3[4], (_Float16)t3[5], (_Float16)t3[6], (_Float16)t3[7] };
    else
        af[6] = *(const f16x8*)(Arow + 192 + quad * 8);
    af[7] = (f16x8){0, 0, 0, 0, 0, 0, 0, 0};
    if (quad == 0) { af[7][0] = (_Float16)t3[8]; af[7][1] = (_Float16)t3[9]; }

    // ---- zero Bt, then stage Wo1 transposed fp16 ----
    {
        int4* bz = (int4*)Bt;
        for (int i = tid; i < 4224; i += 512)
            bz[i] = make_int4(0, 0, 0, 0);
    }
    __syncthreads();
    for (int i = tid; i < 7232; i += 512) {
        int k  = i >> 5;
        int nq = (i & 31) * 4;
        float4 v = *(const float4*)(Wo1 + (size_t)k * 128 + nq);
        Bt[(nq + 0) * BTS + k] = (_Float16)v.x;
        Bt[(nq + 1) * BTS + k] = (_Float16)v.y;
        Bt[(nq + 2) * BTS + k] = (_Float16)v.z;
        Bt[(nq + 3) * BTS + k] = (_Float16)v.w;
    }
    __syncthreads();

    f32x4 acc[8];
    #pragma unroll
    for (int t = 0; t < 8; t++) acc[t] = (f32x4){0.f, 0.f, 0.f, 0.f};

    for (int s = 0; s < 8; s++) {
        #pragma unroll
        for (int t = 0; t < 8; t++) {
            f16x8 bf = *(const f16x8*)&Bt[(t * 16 + ln15) * BTS + s * 32 + quad * 8];
            acc[t] = __builtin_amdgcn_mfma_f32_16x16x32_f16(af[s], bf, acc[t], 0, 0, 0);
        }
    }

    #pragma unroll
    for (int rr = 0; rr < 4; rr++) {
        float p = 0.0f;
        #pragma unroll
        for (int t = 0; t < 8; t++) {
            float h = fmaxf(acc[t][rr] + bo1v[t], 0.0f);
            p += h * wo2v[t];
        }
        p += __shfl_xor(p, 1);
        p += __shfl_xor(p, 2);
        p += __shfl_xor(p, 4);
        p += __shfl_xor(p, 8);
        if (ln15 == rr) {
            int orow = row0 + w * 16 + quad * 4 + rr;
            out[orow] = 1.0f / (1.0f + expf(-(p + bo2v)));
        }
    }
}

// ---------------------------------------------------------------------------
extern "C" void kernel_launch(void* const* d_in, const int* in_sizes, int n_in,
                              void* d_out, int out_size, void* d_ws, size_t ws_size,
                              hipStream_t stream) {
    const float* x        = (const float*)d_in[0];
    const int*   ei       = (const int*)  d_in[1];
    const float* ea       = (const float*)d_in[2];
    const float* gf       = (const float*)d_in[3];
    const float* W_rel1   = (const float*)d_in[4];
    const float* b1       = (const float*)d_in[5];
    const float* W_root1  = (const float*)d_in[6];
    const float* W_rel2   = (const float*)d_in[7];
    const float* b2       = (const float*)d_in[8];
    const float* W_root2  = (const float*)d_in[9];
    const float* Wg1      = (const float*)d_in[10];
    const float* bg1      = (const float*)d_in[11];
    const float* Wg2      = (const float*)d_in[12];
    const float* bg2      = (const float*)d_in[13];
    const float* Wg3      = (const float*)d_in[14];
    const float* bg3      = (const float*)d_in[15];
    const float* Wo1      = (const float*)d_in[16];
    const float* bo1      = (const float*)d_in[17];
    const float* Wo2      = (const float*)d_in[18];
    const float* bo2      = (const float*)d_in[19];

    float* out   = (float*)d_out;
    _Float16* V  = (_Float16*)d_ws;             // [B, VROW] fp16

    const int B = out_size;                     // 32768
    const int E = in_sizes[1] / 2;

    graph_kernel<<<B / GPB, 128, 0, stream>>>(
        x, ei, ea,
        W_rel1, b1, W_root1, W_rel2, b2, W_root2,
        V, E);

    out_mlp_mfma<<<B / 128, 512, 128 * BTS * sizeof(_Float16), stream>>>(
        V, gf, Wg1, bg1, Wg2, bg2, Wg3, bg3, Wo1, bo1, Wo2, bo2, out);
}

// Round 5
// 205.830 us; speedup vs baseline: 1.2279x; 1.0128x over previous
//
#include <hip/hip_runtime.h>
#include <hip/hip_fp16.h>
#include <math.h>

#define NPG 54
#define EPG 144
#define GLOB 10
#define VROW 216   // V row: 216 embeds only (g fused into out_mlp)
#define GPB 2      // graphs (waves) per block in graph_kernel

typedef _Float16 f16x8 __attribute__((ext_vector_type(8)));
typedef _Float16 f16x4 __attribute__((ext_vector_type(4)));
typedef float    f32x4 __attribute__((ext_vector_type(4)));

// Compiler-only memory fence. All LDS hazards in graph_kernel are intra-wave
// DS->DS (zero->atomic, snapshot-read->overlay-write, store->load). The CDNA
// DS pipe processes one wave's LDS instructions IN ORDER (this is what makes
// the compiler's counted lgkmcnt(N) for ds_read->MFMA legal), so no hardware
// drain (s_waitcnt lgkmcnt(0)) is needed -- only compiler ordering. Register
// consumers (MFMA operands) get exact compiler-inserted lgkmcnt waits.
#define CFENCE() asm volatile("" ::: "memory")

// ---------------------------------------------------------------------------
// Kernel 1: one WAVE per graph, operand-SWAPPED dataflow (everything computed
// transposed, C col = node) so every LDS round-trip is a packed b64/b128 op.
// Round-5 change vs round 4: all 6 full lgkmcnt(0) drains (~600 cy/wave of
// forced DS-idle) replaced by zero-cost compiler fences; zeroing trimmed to
// Adj + H1T rows 8..15 only (XT store is unconditional, lanes >=54 write the
// zeros for cols 54..63; cols 64..87 are never read).
//   conv1: agg1^T = X^T @ Adj^T   (A=XT LDS b128 reads, B=Adj b128 frags)
//   lin1 : h1^T   = Wc1^T @ cat^T (wf1 regs as A); h1 -> cat[16..31] packed
//                                  + H1T transposed copy (overwrites XT)
//   conv2: agg2^T = H1T @ Adj^T   (A=H1T b128 rows, B=same Adj frags)
//   lin2 : h2^T   = Wc2^T @ cat^T -> direct packed global V store (no LDS)
// LDS per graph = 8864 B -> 17728 B/block -> 9 blocks/CU = 18 waves.
// ---------------------------------------------------------------------------
struct __align__(16) GL {
    _Float16 Adj[NPG][56];  // 6048 B; after af snapshot, overlaid by cat[64][40]
                            //   cat cols: 0..7 agg1 / 8..15 x  (lin1 K=32)
                            //             0..15 agg2 / 16..31 h1 (lin2 K=32)
    _Float16 H1T[16][88];   // 2816 B, stride 88 halves (176 B, 16B-aligned rows):
                            //   phase 1: XT[feat][node] = x^T   (conv1 A reads)
                            //   phase 2: h1^T[feat][node]       (conv2 A reads)
                            //   cols 54..63 zero throughout (kill k>=54 products)
};

__global__ __launch_bounds__(128, 5) void graph_kernel(
    const float* __restrict__ x,
    const int*   __restrict__ edge_index,
    const float* __restrict__ edge_attr,
    const float* __restrict__ W_rel1, const float* __restrict__ b1,
    const float* __restrict__ W_root1,
    const float* __restrict__ W_rel2, const float* __restrict__ b2,
    const float* __restrict__ W_root2,
    _Float16* __restrict__ v_out,     // [B, VROW] fp16
    int E_total)
{
    __shared__ GL S[GPB];
    const int tid  = threadIdx.x;
    const int w    = tid >> 6;
    const int lane = tid & 63;
    const int ln15 = lane & 15;
    const int quad = lane >> 4;
    const int g    = blockIdx.x * GPB + w;
    GL& L = S[w];
    const int nbase = g * NPG;
    const int ebase = g * EPG;

    _Float16* adjp = &L.Adj[0][0];
    _Float16 (*cat)[40] = (_Float16(*)[40])adjp;   // overlay (rows 0..63, 5120 B)

    // ---- issue global loads FIRST (stay in flight through zeroing) ----
    int   esrc_r[3], edst_r[3];
    float ea_r[3];
    #pragma unroll
    for (int k = 0; k < 3; k++) {
        int e = lane + 64 * k;
        if (e < EPG) {
            esrc_r[k] = edge_index[ebase + e] - nbase;
            edst_r[k] = edge_index[(size_t)E_total + ebase + e] - nbase;
            ea_r[k]   = edge_attr[ebase + e];
        } else { esrc_r[k] = 0; edst_r[k] = -1; ea_r[k] = 0.0f; }
    }
    // coalesced x row load: lane -> node, 2 x float4 (the ONLY x read)
    f16x8 xv = {0, 0, 0, 0, 0, 0, 0, 0};
    if (lane < NPG) {
        const float4* xg4 = (const float4*)(x + (size_t)(nbase + lane) * 8);
        float4 lo = xg4[0], hi = xg4[1];
        xv = (f16x8){ (_Float16)lo.x, (_Float16)lo.y, (_Float16)lo.z, (_Float16)lo.w,
                      (_Float16)hi.x, (_Float16)hi.y, (_Float16)hi.z, (_Float16)hi.w };
    }

    // ---- weight A-fragments in registers (A row = out-feature = ln15) ----
    // wf1[m] = Wcat1[k = quad*8+m][ln15]; k 0..7 = W_rel1, 8..15 = W_root1, rest 0
    f16x8 wf1 = {0, 0, 0, 0, 0, 0, 0, 0};
    if (quad == 0) {
        #pragma unroll
        for (int j = 0; j < 8; j++) wf1[j] = (_Float16)W_rel1[j * 16 + ln15];
    } else if (quad == 1) {
        #pragma unroll
        for (int j = 0; j < 8; j++) wf1[j] = (_Float16)W_root1[j * 16 + ln15];
    }
    // wf2[m] = Wcat2[k = quad*8+m][ln15], valid out < 4; k<16 W_rel2, else W_root2
    f16x8 wf2 = {0, 0, 0, 0, 0, 0, 0, 0};
    if (ln15 < 4) {
        #pragma unroll
        for (int j = 0; j < 8; j++) {
            int k = quad * 8 + j;
            wf2[j] = (_Float16)((k < 16) ? W_rel2[k * 4 + ln15]
                                         : W_root2[(k - 16) * 4 + ln15]);
        }
    }
    // biases: output-feature index is C row = quad*4 + r
    const float4 b1q = *(const float4*)(b1 + quad * 4);
    const float4 b2q = *(const float4*)b2;

    // ---- zero the Adj region only (6048 B = 378 uint4) ----
    {
        uint4* z = (uint4*)&L;
        #pragma unroll
        for (int i = lane; i < 378; i += 64) z[i] = make_uint4(0, 0, 0, 0);
    }
    CFENCE();   // order zeros before atomics (DS in-order per wave does the rest)

    // ---- XT staging: UNCONDITIONAL store fills rows 0..7 cols 0..63
    //      (xv == 0 for lanes >= 54 -> writes the needed zeros at 54..63). ----
    #pragma unroll
    for (int f = 0; f < 8; f++) L.H1T[f][lane] = xv[f];
    // ---- zero H1T rows 8..15 (1408 B = 88 uint4), needed by xA reads ----
    {
        uint4* z2 = (uint4*)&L.H1T[8][0];
        #pragma unroll
        for (int i = lane; i < 88; i += 64) z2[i] = make_uint4(0, 0, 0, 0);
    }
    // ---- build Adj directly: one ds_pk_add_f16 per edge (dups sum in HW) ----
    #pragma unroll
    for (int k = 0; k < 3; k++) {
        if (edst_r[k] >= 0) {
            int s = esrc_r[k];
            __half2* cell = (__half2*)&L.Adj[edst_r[k]][s & ~1];
            __half a16 = __float2half(ea_r[k]);
            __half z16 = __float2half(0.0f);
            __half2 val = (s & 1) ? __halves2half2(z16, a16)
                                  : __halves2half2(a16, z16);
            unsafeAtomicAdd(cell, val);
        }
    }
    CFENCE();   // atomics ordered before af/xA reads (in-order DS)

    // ---- Adj^T B-fragments -> regs, reused by BOTH convs.
    //      af[t][c][m] = Adj[dst = t*16+ln15][src = c*32+quad*8+m].
    //      Rows >= 54 read XT/garbage: those C-cols are node >= 54, never
    //      stored to V. k >= 54 products are killed by zero xA/hA cols. ----
    f16x8 af[4][2];
    #pragma unroll
    for (int t = 0; t < 4; t++)
        #pragma unroll
        for (int c = 0; c < 2; c++)
            af[t][c] = *(const f16x8*)(adjp + (t * 16 + ln15) * 56 + c * 32 + quad * 8);
    // ---- X^T A-fragments from XT: xA[c][m] = x[src = c*32+quad*8+m][ln15].
    //      Rows 8..15 (ln15 >= 8) and cols >= 54 are zero -> clean zeros. ----
    f16x8 xA[2];
    #pragma unroll
    for (int c = 0; c < 2; c++)
        xA[c] = *(const f16x8*)&L.H1T[ln15][c * 32 + quad * 8];
    CFENCE();   // keep cat overlay writes (below) after these reads (WAR, in-order)

    // ---- conv1: agg1^T = X^T @ Adj^T (C: col=node=t*16+ln15, row=feat=quad*4+r) ----
    f32x4 acc1[4];
    #pragma unroll
    for (int t = 0; t < 4; t++) acc1[t] = (f32x4){0.f, 0.f, 0.f, 0.f};
    #pragma unroll
    for (int c = 0; c < 2; c++)
        #pragma unroll
        for (int t = 0; t < 4; t++)
            acc1[t] = __builtin_amdgcn_mfma_f32_16x16x32_f16(xA[c], af[t][c], acc1[t], 0, 0, 0);
    // packed stores: agg1 feats 0..7 live in quads 0,1 -> cat[node][quad*4..+3]
    // (quads 2,3 are structural zeros and MUST NOT store: cols 8..15 belong to xv)
    if (quad < 2) {
        #pragma unroll
        for (int t = 0; t < 4; t++) {
            f16x4 ap;
            #pragma unroll
            for (int r = 0; r < 4; r++) ap[r] = (_Float16)acc1[t][r];
            *(f16x4*)&cat[t * 16 + ln15][quad * 4] = ap;
        }
    }
    if (lane < NPG) *(f16x8*)&cat[lane][8] = xv;   // root features, cols 8..15
    CFENCE();

    // ---- lin1: h1^T = Wc1^T @ cat^T + b1, relu.
    //      Store h1 twice: packed to cat[node][16+quad*4] (lin2 B operand),
    //      and transposed to H1T[feat][node] (conv2 A operand; overwrites XT:
    //      rows 0..15 cols < 54 rewritten, cols 54..63 stay zero). ----
    f32x4 ci1 = {b1q.x, b1q.y, b1q.z, b1q.w};
    #pragma unroll
    for (int t = 0; t < 4; t++) {
        f16x8 bc = *(const f16x8*)&cat[t * 16 + ln15][quad * 8];  // k 16..31: garbage x wf1=0
        f32x4 hL = __builtin_amdgcn_mfma_f32_16x16x32_f16(wf1, bc, ci1, 0, 0, 0);
        int node = t * 16 + ln15;
        f16x4 hp;
        #pragma unroll
        for (int r = 0; r < 4; r++) hp[r] = (_Float16)fmaxf(hL[r], 0.0f);
        *(f16x4*)&cat[node][16 + quad * 4] = hp;         // rows >=54 nonzero, guarded later
        if (node < NPG) {                                 // H1T cols 54..63 stay ZERO
            #pragma unroll
            for (int r = 0; r < 4; r++) L.H1T[quad * 4 + r][node] = hp[r];
        }
    }
    CFENCE();

    // ---- conv2: agg2^T = H1T @ Adj^T; A-frags are packed H1T row reads ----
    f16x8 hA[2];
    #pragma unroll
    for (int c = 0; c < 2; c++)
        hA[c] = *(const f16x8*)&L.H1T[ln15][c * 32 + quad * 8];
    f32x4 acc2[4];
    #pragma unroll
    for (int t = 0; t < 4; t++) acc2[t] = (f32x4){0.f, 0.f, 0.f, 0.f};
    #pragma unroll
    for (int c = 0; c < 2; c++)
        #pragma unroll
        for (int t = 0; t < 4; t++)
            acc2[t] = __builtin_amdgcn_mfma_f32_16x16x32_f16(hA[c], af[t][c], acc2[t], 0, 0, 0);
    // agg2 feats 0..15 -> cat cols 0..15 (agg1/xv dead); h1 in 16..31 untouched
    #pragma unroll
    for (int t = 0; t < 4; t++) {
        f16x4 ap;
        #pragma unroll
        for (int r = 0; r < 4; r++) ap[r] = (_Float16)acc2[t][r];
        *(f16x4*)&cat[t * 16 + ln15][quad * 4] = ap;
    }
    CFENCE();

    // ---- lin2: h2^T = Wc2^T @ [agg2|h1]^T + b2, relu; direct global V store ----
    f32x4 ci2 = {b2q.x, b2q.y, b2q.z, b2q.w};
    #pragma unroll
    for (int t = 0; t < 4; t++) {
        int node = t * 16 + ln15;
        f16x8 bv = *(const f16x8*)&cat[node][quad * 8];
        f32x4 o = __builtin_amdgcn_mfma_f32_16x16x32_f16(wf2, bv, ci2, 0, 0, 0);
        if (quad == 0 && node < NPG) {     // real outputs = rows 0..3 = quad 0
            f16x4 vp;
            #pragma unroll
            for (int r = 0; r < 4; r++) vp[r] = (_Float16)fmaxf(o[r], 0.0f);
            *(f16x4*)(v_out + (size_t)g * VROW + node * 4) = vp;
        }
    }
}

// ---------------------------------------------------------------------------
// Kernel 2: out-MLP via fp16 MFMA (unchanged: LDS Bt staging, 512 threads),
// with the 10->8->8->10 global MLP fused per-lane in fp32.
// ---------------------------------------------------------------------------
#define BTS 264

__global__ __launch_bounds__(512) void out_mlp_mfma(
    const _Float16* __restrict__ V,    // [B, VROW] fp16
    const float* __restrict__ gf,      // [B, 10]
    const float* __restrict__ Wg1, const float* __restrict__ bg1,
    const float* __restrict__ Wg2, const float* __restrict__ bg2,
    const float* __restrict__ Wg3, const float* __restrict__ bg3,
    const float* __restrict__ Wo1,     // [226, 128] fp32
    const float* __restrict__ bo1,
    const float* __restrict__ Wo2,
    const float* __restrict__ bo2,
    float* __restrict__ out)
{
    extern __shared__ _Float16 Bt[];   // [128][BTS] = 67584 B

    const int tid  = threadIdx.x;
    const int w    = tid >> 6;
    const int lane = tid & 63;
    const int ln15 = lane & 15;
    const int quad = lane >> 4;
    const int row0 = blockIdx.x * 128;
    const int row  = row0 + w * 16 + ln15;

    float bo1v[8], wo2v[8];
    #pragma unroll
    for (int t = 0; t < 8; t++) {
        bo1v[t] = bo1[t * 16 + ln15];
        wo2v[t] = Wo2[t * 16 + ln15];
    }
    const float bo2v = bo2[0];

    // ---- per-lane global-MLP for this lane's row (fp32) ----
    float t3[GLOB];
    {
        const float* gr = gf + (size_t)row * GLOB;
        float t0[GLOB];
        #pragma unroll
        for (int i = 0; i < GLOB; i++) t0[i] = gr[i];
        float t1[8];
        #pragma unroll
        for (int j = 0; j < 8; j++) {
            float a = bg1[j];
            #pragma unroll
            for (int i = 0; i < GLOB; i++) a += t0[i] * Wg1[i * 8 + j];
            t1[j] = fmaxf(a, 0.0f);
        }
        float t2[8];
        #pragma unroll
        for (int j = 0; j < 8; j++) {
            float a = bg2[j];
            #pragma unroll
            for (int i = 0; i < 8; i++) a += t1[i] * Wg2[i * 8 + j];
            t2[j] = fmaxf(a, 0.0f);
        }
        #pragma unroll
        for (int j = 0; j < GLOB; j++) {
            float a = bg3[j];
            #pragma unroll
            for (int i = 0; i < 8; i++) a += t2[i] * Wg3[i * GLOB + j];
            t3[j] = fmaxf(a, 0.0f);
        }
    }

    // ---- A-fragments: s<6 from V; s=6 quad3 + s=7 quad0 from g ----
    const _Float16* Arow = V + (size_t)row * VROW;
    f16x8 af[8];
    #pragma unroll
    for (int s = 0; s < 6; s++)
        af[s] = *(const f16x8*)(Arow + s * 32 + quad * 8);
    if (quad == 3)
        af[6] = (f16x8){ (_Float16)t3[0], (_Float16)t3[1], (_Float16)t3[2], (_Float16)t3[3],
                         (_Float16)t3[4], (_Float16)t3[5], (_Float16)t3[6], (_Float16)t3[7] };
    else
        af[6] = *(const f16x8*)(Arow + 192 + quad * 8);
    af[7] = (f16x8){0, 0, 0, 0, 0, 0, 0, 0};
    if (quad == 0) { af[7][0] = (_Float16)t3[8]; af[7][1] = (_Float16)t3[9]; }

    // ---- zero Bt, then stage Wo1 transposed fp16 ----
    {
        int4* bz = (int4*)Bt;
        for (int i = tid; i < 4224; i += 512)
            bz[i] = make_int4(0, 0, 0, 0);
    }
    __syncthreads();
    for (int i = tid; i < 7232; i += 512) {
        int k  = i >> 5;
        int nq = (i & 31) * 4;
        float4 v = *(const float4*)(Wo1 + (size_t)k * 128 + nq);
        Bt[(nq + 0) * BTS + k] = (_Float16)v.x;
        Bt[(nq + 1) * BTS + k] = (_Float16)v.y;
        Bt[(nq + 2) * BTS + k] = (_Float16)v.z;
        Bt[(nq + 3) * BTS + k] = (_Float16)v.w;
    }
    __syncthreads();

    f32x4 acc[8];
    #pragma unroll
    for (int t = 0; t < 8; t++) acc[t] = (f32x4){0.f, 0.f, 0.f, 0.f};

    for (int s = 0; s < 8; s++) {
        #pragma unroll
        for (int t = 0; t < 8; t++) {
            f16x8 bf = *(const f16x8*)&Bt[(t * 16 + ln15) * BTS + s * 32 + quad * 8];
            acc[t] = __builtin_amdgcn_mfma_f32_16x16x32_f16(af[s], bf, acc[t], 0, 0, 0);
        }
    }

    #pragma unroll
    for (int rr = 0; rr < 4; rr++) {
        float p = 0.0f;
        #pragma unroll
        for (int t = 0; t < 8; t++) {
            float h = fmaxf(acc[t][rr] + bo1v[t], 0.0f);
            p += h * wo2v[t];
        }
        p += __shfl_xor(p, 1);
        p += __shfl_xor(p, 2);
        p += __shfl_xor(p, 4);
        p += __shfl_xor(p, 8);
        if (ln15 == rr) {
            int orow = row0 + w * 16 + quad * 4 + rr;
            out[orow] = 1.0f / (1.0f + expf(-(p + bo2v)));
        }
    }
}

// ---------------------------------------------------------------------------
extern "C" void kernel_launch(void* const* d_in, const int* in_sizes, int n_in,
                              void* d_out, int out_size, void* d_ws, size_t ws_size,
                              hipStream_t stream) {
    const float* x        = (const float*)d_in[0];
    const int*   ei       = (const int*)  d_in[1];
    const float* ea       = (const float*)d_in[2];
    const float* gf       = (const float*)d_in[3];
    const float* W_rel1   = (const float*)d_in[4];
    const float* b1       = (const float*)d_in[5];
    const float* W_root1  = (const float*)d_in[6];
    const float* W_rel2   = (const float*)d_in[7];
    const float* b2       = (const float*)d_in[8];
    const float* W_root2  = (const float*)d_in[9];
    const float* Wg1      = (const float*)d_in[10];
    const float* bg1      = (const float*)d_in[11];
    const float* Wg2      = (const float*)d_in[12];
    const float* bg2      = (const float*)d_in[13];
    const float* Wg3      = (const float*)d_in[14];
    const float* bg3      = (const float*)d_in[15];
    const float* Wo1      = (const float*)d_in[16];
    const float* bo1      = (const float*)d_in[17];
    const float* Wo2      = (const float*)d_in[18];
    const float* bo2      = (const float*)d_in[19];

    float* out   = (float*)d_out;
    _Float16* V  = (_Float16*)d_ws;             // [B, VROW] fp16

    const int B = out_size;                     // 32768
    const int E = in_sizes[1] / 2;

    graph_kernel<<<B / GPB, 128, 0, stream>>>(
        x, ei, ea,
        W_rel1, b1, W_root1, W_rel2, b2, W_root2,
        V, E);

    out_mlp_mfma<<<B / 128, 512, 128 * BTS * sizeof(_Float16), stream>>>(
        V, gf, Wg1, bg1, Wg2, bg2, Wg3, bg3, Wo1, bo1, Wo2, bo2, out);
}

// Round 6
// 203.225 us; speedup vs baseline: 1.2436x; 1.0128x over previous
//
#include <hip/hip_runtime.h>
#include <hip/hip_fp16.h>
#include <math.h>

#define NPG 54
#define EPG 144
#define GLOB 10
#define VROW 216   // V row: 216 embeds only (g fused into out_mlp)
#define GPB 2      // graphs (waves) per block in graph_kernel

typedef _Float16 f16x8 __attribute__((ext_vector_type(8)));
typedef _Float16 f16x4 __attribute__((ext_vector_type(4)));
typedef float    f32x4 __attribute__((ext_vector_type(4)));

// Compiler-only memory fence (intra-wave DS->DS hazards; DS pipe is in-order
// per wave, so no hardware drain needed -- R5-verified correct).
#define CFENCE() asm volatile("" ::: "memory")

// ---------------------------------------------------------------------------
// Kernel 1: one WAVE per graph, operand-SWAPPED dataflow (everything computed
// transposed, C col = node). UNCHANGED from round 5 (64.4 us, passed).
// ---------------------------------------------------------------------------
struct __align__(16) GL {
    _Float16 Adj[NPG][56];  // 6048 B; after af snapshot, overlaid by cat[64][40]
    _Float16 H1T[16][88];   // 2816 B: XT then h1^T, [feat][node]
};

__global__ __launch_bounds__(128, 5) void graph_kernel(
    const float* __restrict__ x,
    const int*   __restrict__ edge_index,
    const float* __restrict__ edge_attr,
    const float* __restrict__ W_rel1, const float* __restrict__ b1,
    const float* __restrict__ W_root1,
    const float* __restrict__ W_rel2, const float* __restrict__ b2,
    const float* __restrict__ W_root2,
    _Float16* __restrict__ v_out,     // [B, VROW] fp16
    int E_total)
{
    __shared__ GL S[GPB];
    const int tid  = threadIdx.x;
    const int w    = tid >> 6;
    const int lane = tid & 63;
    const int ln15 = lane & 15;
    const int quad = lane >> 4;
    const int g    = blockIdx.x * GPB + w;
    GL& L = S[w];
    const int nbase = g * NPG;
    const int ebase = g * EPG;

    _Float16* adjp = &L.Adj[0][0];
    _Float16 (*cat)[40] = (_Float16(*)[40])adjp;   // overlay (rows 0..63, 5120 B)

    // ---- issue global loads FIRST (stay in flight through zeroing) ----
    int   esrc_r[3], edst_r[3];
    float ea_r[3];
    #pragma unroll
    for (int k = 0; k < 3; k++) {
        int e = lane + 64 * k;
        if (e < EPG) {
            esrc_r[k] = edge_index[ebase + e] - nbase;
            edst_r[k] = edge_index[(size_t)E_total + ebase + e] - nbase;
            ea_r[k]   = edge_attr[ebase + e];
        } else { esrc_r[k] = 0; edst_r[k] = -1; ea_r[k] = 0.0f; }
    }
    // coalesced x row load: lane -> node, 2 x float4 (the ONLY x read)
    f16x8 xv = {0, 0, 0, 0, 0, 0, 0, 0};
    if (lane < NPG) {
        const float4* xg4 = (const float4*)(x + (size_t)(nbase + lane) * 8);
        float4 lo = xg4[0], hi = xg4[1];
        xv = (f16x8){ (_Float16)lo.x, (_Float16)lo.y, (_Float16)lo.z, (_Float16)lo.w,
                      (_Float16)hi.x, (_Float16)hi.y, (_Float16)hi.z, (_Float16)hi.w };
    }

    // ---- weight A-fragments in registers (A row = out-feature = ln15) ----
    f16x8 wf1 = {0, 0, 0, 0, 0, 0, 0, 0};
    if (quad == 0) {
        #pragma unroll
        for (int j = 0; j < 8; j++) wf1[j] = (_Float16)W_rel1[j * 16 + ln15];
    } else if (quad == 1) {
        #pragma unroll
        for (int j = 0; j < 8; j++) wf1[j] = (_Float16)W_root1[j * 16 + ln15];
    }
    f16x8 wf2 = {0, 0, 0, 0, 0, 0, 0, 0};
    if (ln15 < 4) {
        #pragma unroll
        for (int j = 0; j < 8; j++) {
            int k = quad * 8 + j;
            wf2[j] = (_Float16)((k < 16) ? W_rel2[k * 4 + ln15]
                                         : W_root2[(k - 16) * 4 + ln15]);
        }
    }
    const float4 b1q = *(const float4*)(b1 + quad * 4);
    const float4 b2q = *(const float4*)b2;

    // ---- zero the Adj region only (6048 B = 378 uint4) ----
    {
        uint4* z = (uint4*)&L;
        #pragma unroll
        for (int i = lane; i < 378; i += 64) z[i] = make_uint4(0, 0, 0, 0);
    }
    CFENCE();

    // ---- XT staging: unconditional, lanes >= 54 write zeros at cols 54..63 ----
    #pragma unroll
    for (int f = 0; f < 8; f++) L.H1T[f][lane] = xv[f];
    // ---- zero H1T rows 8..15 (88 uint4) ----
    {
        uint4* z2 = (uint4*)&L.H1T[8][0];
        #pragma unroll
        for (int i = lane; i < 88; i += 64) z2[i] = make_uint4(0, 0, 0, 0);
    }
    // ---- build Adj: one ds_pk_add_f16 per edge (dups sum in HW) ----
    #pragma unroll
    for (int k = 0; k < 3; k++) {
        if (edst_r[k] >= 0) {
            int s = esrc_r[k];
            __half2* cell = (__half2*)&L.Adj[edst_r[k]][s & ~1];
            __half a16 = __float2half(ea_r[k]);
            __half z16 = __float2half(0.0f);
            __half2 val = (s & 1) ? __halves2half2(z16, a16)
                                  : __halves2half2(a16, z16);
            unsafeAtomicAdd(cell, val);
        }
    }
    CFENCE();

    // ---- Adj^T B-fragments -> regs, reused by BOTH convs ----
    f16x8 af[4][2];
    #pragma unroll
    for (int t = 0; t < 4; t++)
        #pragma unroll
        for (int c = 0; c < 2; c++)
            af[t][c] = *(const f16x8*)(adjp + (t * 16 + ln15) * 56 + c * 32 + quad * 8);
    // ---- X^T A-fragments from XT ----
    f16x8 xA[2];
    #pragma unroll
    for (int c = 0; c < 2; c++)
        xA[c] = *(const f16x8*)&L.H1T[ln15][c * 32 + quad * 8];
    CFENCE();

    // ---- conv1: agg1^T = X^T @ Adj^T ----
    f32x4 acc1[4];
    #pragma unroll
    for (int t = 0; t < 4; t++) acc1[t] = (f32x4){0.f, 0.f, 0.f, 0.f};
    #pragma unroll
    for (int c = 0; c < 2; c++)
        #pragma unroll
        for (int t = 0; t < 4; t++)
            acc1[t] = __builtin_amdgcn_mfma_f32_16x16x32_f16(xA[c], af[t][c], acc1[t], 0, 0, 0);
    if (quad < 2) {
        #pragma unroll
        for (int t = 0; t < 4; t++) {
            f16x4 ap;
            #pragma unroll
            for (int r = 0; r < 4; r++) ap[r] = (_Float16)acc1[t][r];
            *(f16x4*)&cat[t * 16 + ln15][quad * 4] = ap;
        }
    }
    if (lane < NPG) *(f16x8*)&cat[lane][8] = xv;   // root features, cols 8..15
    CFENCE();

    // ---- lin1: h1^T = Wc1^T @ cat^T + b1, relu; dual store ----
    f32x4 ci1 = {b1q.x, b1q.y, b1q.z, b1q.w};
    #pragma unroll
    for (int t = 0; t < 4; t++) {
        f16x8 bc = *(const f16x8*)&cat[t * 16 + ln15][quad * 8];
        f32x4 hL = __builtin_amdgcn_mfma_f32_16x16x32_f16(wf1, bc, ci1, 0, 0, 0);
        int node = t * 16 + ln15;
        f16x4 hp;
        #pragma unroll
        for (int r = 0; r < 4; r++) hp[r] = (_Float16)fmaxf(hL[r], 0.0f);
        *(f16x4*)&cat[node][16 + quad * 4] = hp;
        if (node < NPG) {
            #pragma unroll
            for (int r = 0; r < 4; r++) L.H1T[quad * 4 + r][node] = hp[r];
        }
    }
    CFENCE();

    // ---- conv2: agg2^T = H1T @ Adj^T ----
    f16x8 hA[2];
    #pragma unroll
    for (int c = 0; c < 2; c++)
        hA[c] = *(const f16x8*)&L.H1T[ln15][c * 32 + quad * 8];
    f32x4 acc2[4];
    #pragma unroll
    for (int t = 0; t < 4; t++) acc2[t] = (f32x4){0.f, 0.f, 0.f, 0.f};
    #pragma unroll
    for (int c = 0; c < 2; c++)
        #pragma unroll
        for (int t = 0; t < 4; t++)
            acc2[t] = __builtin_amdgcn_mfma_f32_16x16x32_f16(hA[c], af[t][c], acc2[t], 0, 0, 0);
    #pragma unroll
    for (int t = 0; t < 4; t++) {
        f16x4 ap;
        #pragma unroll
        for (int r = 0; r < 4; r++) ap[r] = (_Float16)acc2[t][r];
        *(f16x4*)&cat[t * 16 + ln15][quad * 4] = ap;
    }
    CFENCE();

    // ---- lin2: h2^T = Wc2^T @ [agg2|h1]^T + b2, relu; direct global V store ----
    f32x4 ci2 = {b2q.x, b2q.y, b2q.z, b2q.w};
    #pragma unroll
    for (int t = 0; t < 4; t++) {
        int node = t * 16 + ln15;
        f16x8 bv = *(const f16x8*)&cat[node][quad * 8];
        f32x4 o = __builtin_amdgcn_mfma_f32_16x16x32_f16(wf2, bv, ci2, 0, 0, 0);
        if (quad == 0 && node < NPG) {
            f16x4 vp;
            #pragma unroll
            for (int r = 0; r < 4; r++) vp[r] = (_Float16)fmaxf(o[r], 0.0f);
            *(f16x4*)(v_out + (size_t)g * VROW + node * 4) = vp;
        }
    }
}

// ---------------------------------------------------------------------------
// Prep kernel: WT = Wo1^T in fp16, already in Bt's exact [128][BTS] padded
// layout (k >= 226 zeroed). Runs once per launch (~68 KB). This hoists the
// transpose OUT of out_mlp, whose per-block LDS transpose stores were a
// 32-way bank conflict (2 banks per 64-lane store) x 56.5 stores/lane.
// ---------------------------------------------------------------------------
#define BTS 264

__global__ __launch_bounds__(320) void wo1t_prep(
    const float* __restrict__ Wo1,    // [226, 128] fp32
    _Float16* __restrict__ WT)        // [128, BTS] fp16
{
    const int n = blockIdx.x;         // 0..127 output row
    const int k = threadIdx.x;        // 0..319
    if (k < BTS) {
        _Float16 v = (_Float16)0.0f;
        if (k < 226) v = (_Float16)Wo1[(size_t)k * 128 + n];
        WT[(size_t)n * BTS + k] = v;  // coalesced write
    }
}

// ---------------------------------------------------------------------------
// Kernel 2 (new): out-MLP via fp16 MFMA. Bt filled by a LINEAR int4 copy of
// WT (conflict-free b128 stores, no zero pass, one barrier) instead of the
// in-kernel fp32->fp16 transpose. Bt content is byte-identical to before.
// ---------------------------------------------------------------------------
__global__ __launch_bounds__(512) void out_mlp_mfma2(
    const _Float16* __restrict__ V,    // [B, VROW] fp16
    const _Float16* __restrict__ WT,   // [128, BTS] fp16 (pre-transposed Wo1)
    const float* __restrict__ gf,      // [B, 10]
    const float* __restrict__ Wg1, const float* __restrict__ bg1,
    const float* __restrict__ Wg2, const float* __restrict__ bg2,
    const float* __restrict__ Wg3, const float* __restrict__ bg3,
    const float* __restrict__ bo1,
    const float* __restrict__ Wo2,
    const float* __restrict__ bo2,
    float* __restrict__ out)
{
    extern __shared__ _Float16 Bt[];   // [128][BTS] = 67584 B

    const int tid  = threadIdx.x;
    const int w    = tid >> 6;
    const int lane = tid & 63;
    const int ln15 = lane & 15;
    const int quad = lane >> 4;
    const int row0 = blockIdx.x * 128;
    const int row  = row0 + w * 16 + ln15;

    float bo1v[8], wo2v[8];
    #pragma unroll
    for (int t = 0; t < 8; t++) {
        bo1v[t] = bo1[t * 16 + ln15];
        wo2v[t] = Wo2[t * 16 + ln15];
    }
    const float bo2v = bo2[0];

    // ---- per-lane global-MLP for this lane's row (fp32) ----
    float t3[GLOB];
    {
        const float* gr = gf + (size_t)row * GLOB;
        float t0[GLOB];
        #pragma unroll
        for (int i = 0; i < GLOB; i++) t0[i] = gr[i];
        float t1[8];
        #pragma unroll
        for (int j = 0; j < 8; j++) {
            float a = bg1[j];
            #pragma unroll
            for (int i = 0; i < GLOB; i++) a += t0[i] * Wg1[i * 8 + j];
            t1[j] = fmaxf(a, 0.0f);
        }
        float t2[8];
        #pragma unroll
        for (int j = 0; j < 8; j++) {
            float a = bg2[j];
            #pragma unroll
            for (int i = 0; i < 8; i++) a += t1[i] * Wg2[i * 8 + j];
            t2[j] = fmaxf(a, 0.0f);
        }
        #pragma unroll
        for (int j = 0; j < GLOB; j++) {
            float a = bg3[j];
            #pragma unroll
            for (int i = 0; i < 8; i++) a += t2[i] * Wg3[i * GLOB + j];
            t3[j] = fmaxf(a, 0.0f);
        }
    }

    // ---- A-fragments: s<6 from V; s=6 quad3 + s=7 quad0 from g ----
    const _Float16* Arow = V + (size_t)row * VROW;
    f16x8 af[8];
    #pragma unroll
    for (int s = 0; s < 6; s++)
        af[s] = *(const f16x8*)(Arow + s * 32 + quad * 8);
    if (quad == 3)
        af[6] = (f16x8){ (_Float16)t3[0], (_Float16)t3[1], (_Float16)t3[2], (_Float16)t3[3],
                         (_Float16)t3[4], (_Float16)t3[5], (_Float16)t3[6], (_Float16)t3[7] };
    else
        af[6] = *(const f16x8*)(Arow + 192 + quad * 8);
    af[7] = (f16x8){0, 0, 0, 0, 0, 0, 0, 0};
    if (quad == 0) { af[7][0] = (_Float16)t3[8]; af[7][1] = (_Float16)t3[9]; }

    // ---- Bt <- WT: linear int4 copy (conflict-free), 4224 int4 ----
    {
        const int4* wt4 = (const int4*)WT;
        int4* bt4 = (int4*)Bt;
        for (int i = tid; i < 4224; i += 512) bt4[i] = wt4[i];
    }
    __syncthreads();

    f32x4 acc[8];
    #pragma unroll
    for (int t = 0; t < 8; t++) acc[t] = (f32x4){0.f, 0.f, 0.f, 0.f};

    for (int s = 0; s < 8; s++) {
        #pragma unroll
        for (int t = 0; t < 8; t++) {
            f16x8 bf = *(const f16x8*)&Bt[(t * 16 + ln15) * BTS + s * 32 + quad * 8];
            acc[t] = __builtin_amdgcn_mfma_f32_16x16x32_f16(af[s], bf, acc[t], 0, 0, 0);
        }
    }

    #pragma unroll
    for (int rr = 0; rr < 4; rr++) {
        float p = 0.0f;
        #pragma unroll
        for (int t = 0; t < 8; t++) {
            float h = fmaxf(acc[t][rr] + bo1v[t], 0.0f);
            p += h * wo2v[t];
        }
        p += __shfl_xor(p, 1);
        p += __shfl_xor(p, 2);
        p += __shfl_xor(p, 4);
        p += __shfl_xor(p, 8);
        if (ln15 == rr) {
            int orow = row0 + w * 16 + quad * 4 + rr;
            out[orow] = 1.0f / (1.0f + expf(-(p + bo2v)));
        }
    }
}

// ---------------------------------------------------------------------------
// Kernel 2 (fallback, ws too small): original in-kernel staging version.
// ---------------------------------------------------------------------------
__global__ __launch_bounds__(512) void out_mlp_mfma(
    const _Float16* __restrict__ V,
    const float* __restrict__ gf,
    const float* __restrict__ Wg1, const float* __restrict__ bg1,
    const float* __restrict__ Wg2, const float* __restrict__ bg2,
    const float* __restrict__ Wg3, const float* __restrict__ bg3,
    const float* __restrict__ Wo1,
    const float* __restrict__ bo1,
    const float* __restrict__ Wo2,
    const float* __restrict__ bo2,
    float* __restrict__ out)
{
    extern __shared__ _Float16 Bt[];

    const int tid  = threadIdx.x;
    const int w    = tid >> 6;
    const int lane = tid & 63;
    const int ln15 = lane & 15;
    const int quad = lane >> 4;
    const int row0 = blockIdx.x * 128;
    const int row  = row0 + w * 16 + ln15;

    float bo1v[8], wo2v[8];
    #pragma unroll
    for (int t = 0; t < 8; t++) {
        bo1v[t] = bo1[t * 16 + ln15];
        wo2v[t] = Wo2[t * 16 + ln15];
    }
    const float bo2v = bo2[0];

    float t3[GLOB];
    {
        const float* gr = gf + (size_t)row * GLOB;
        float t0[GLOB];
        #pragma unroll
        for (int i = 0; i < GLOB; i++) t0[i] = gr[i];
        float t1[8];
        #pragma unroll
        for (int j = 0; j < 8; j++) {
            float a = bg1[j];
            #pragma unroll
            for (int i = 0; i < GLOB; i++) a += t0[i] * Wg1[i * 8 + j];
            t1[j] = fmaxf(a, 0.0f);
        }
        float t2[8];
        #pragma unroll
        for (int j = 0; j < 8; j++) {
            float a = bg2[j];
            #pragma unroll
            for (int i = 0; i < 8; i++) a += t1[i] * Wg2[i * 8 + j];
            t2[j] = fmaxf(a, 0.0f);
        }
        #pragma unroll
        for (int j = 0; j < GLOB; j++) {
            float a = bg3[j];
            #pragma unroll
            for (int i = 0; i < 8; i++) a += t2[i] * Wg3[i * GLOB + j];
            t3[j] = fmaxf(a, 0.0f);
        }
    }

    const _Float16* Arow = V + (size_t)row * VROW;
    f16x8 af[8];
    #pragma unroll
    for (int s = 0; s < 6; s++)
        af[s] = *(const f16x8*)(Arow + s * 32 + quad * 8);
    if (quad == 3)
        af[6] = (f16x8){ (_Float16)t3[0], (_Float16)t3[1], (_Float16)t3[2], (_Float16)t3[3],
                         (_Float16)t3[4], (_Float16)t3[5], (_Float16)t3[6], (_Float16)t3[7] };
    else
        af[6] = *(const f16x8*)(Arow + 192 + quad * 8);
    af[7] = (f16x8){0, 0, 0, 0, 0, 0, 0, 0};
    if (quad == 0) { af[7][0] = (_Float16)t3[8]; af[7][1] = (_Float16)t3[9]; }

    {
        int4* bz = (int4*)Bt;
        for (int i = tid; i < 4224; i += 512)
            bz[i] = make_int4(0, 0, 0, 0);
    }
    __syncthreads();
    for (int i = tid; i < 7232; i += 512) {
        int k  = i >> 5;
        int nq = (i & 31) * 4;
        float4 v = *(const float4*)(Wo1 + (size_t)k * 128 + nq);
        Bt[(nq + 0) * BTS + k] = (_Float16)v.x;
        Bt[(nq + 1) * BTS + k] = (_Float16)v.y;
        Bt[(nq + 2) * BTS + k] = (_Float16)v.z;
        Bt[(nq + 3) * BTS + k] = (_Float16)v.w;
    }
    __syncthreads();

    f32x4 acc[8];
    #pragma unroll
    for (int t = 0; t < 8; t++) acc[t] = (f32x4){0.f, 0.f, 0.f, 0.f};

    for (int s = 0; s < 8; s++) {
        #pragma unroll
        for (int t = 0; t < 8; t++) {
            f16x8 bf = *(const f16x8*)&Bt[(t * 16 + ln15) * BTS + s * 32 + quad * 8];
            acc[t] = __builtin_amdgcn_mfma_f32_16x16x32_f16(af[s], bf, acc[t], 0, 0, 0);
        }
    }

    #pragma unroll
    for (int rr = 0; rr < 4; rr++) {
        float p = 0.0f;
        #pragma unroll
        for (int t = 0; t < 8; t++) {
            float h = fmaxf(acc[t][rr] + bo1v[t], 0.0f);
            p += h * wo2v[t];
        }
        p += __shfl_xor(p, 1);
        p += __shfl_xor(p, 2);
        p += __shfl_xor(p, 4);
        p += __shfl_xor(p, 8);
        if (ln15 == rr) {
            int orow = row0 + w * 16 + quad * 4 + rr;
            out[orow] = 1.0f / (1.0f + expf(-(p + bo2v)));
        }
    }
}

// ---------------------------------------------------------------------------
extern "C" void kernel_launch(void* const* d_in, const int* in_sizes, int n_in,
                              void* d_out, int out_size, void* d_ws, size_t ws_size,
                              hipStream_t stream) {
    const float* x        = (const float*)d_in[0];
    const int*   ei       = (const int*)  d_in[1];
    const float* ea       = (const float*)d_in[2];
    const float* gf       = (const float*)d_in[3];
    const float* W_rel1   = (const float*)d_in[4];
    const float* b1       = (const float*)d_in[5];
    const float* W_root1  = (const float*)d_in[6];
    const float* W_rel2   = (const float*)d_in[7];
    const float* b2       = (const float*)d_in[8];
    const float* W_root2  = (const float*)d_in[9];
    const float* Wg1      = (const float*)d_in[10];
    const float* bg1      = (const float*)d_in[11];
    const float* Wg2      = (const float*)d_in[12];
    const float* bg2      = (const float*)d_in[13];
    const float* Wg3      = (const float*)d_in[14];
    const float* bg3      = (const float*)d_in[15];
    const float* Wo1      = (const float*)d_in[16];
    const float* bo1      = (const float*)d_in[17];
    const float* Wo2      = (const float*)d_in[18];
    const float* bo2      = (const float*)d_in[19];

    float* out   = (float*)d_out;
    _Float16* V  = (_Float16*)d_ws;             // [B, VROW] fp16

    const int B = out_size;                     // 32768
    const int E = in_sizes[1] / 2;

    const size_t VBYTES  = (size_t)B * VROW * sizeof(_Float16);
    const size_t WTBYTES = (size_t)128 * BTS * sizeof(_Float16);
    _Float16* WT = (_Float16*)((char*)d_ws + VBYTES);
    const bool use_prep = (ws_size >= VBYTES + WTBYTES);

    if (use_prep)
        wo1t_prep<<<128, 320, 0, stream>>>(Wo1, WT);

    graph_kernel<<<B / GPB, 128, 0, stream>>>(
        x, ei, ea,
        W_rel1, b1, W_root1, W_rel2, b2, W_root2,
        V, E);

    if (use_prep)
        out_mlp_mfma2<<<B / 128, 512, 128 * BTS * sizeof(_Float16), stream>>>(
            V, WT, gf, Wg1, bg1, Wg2, bg2, Wg3, bg3, bo1, Wo2, bo2, out);
    else
        out_mlp_mfma<<<B / 128, 512, 128 * BTS * sizeof(_Float16), stream>>>(
            V, gf, Wg1, bg1, Wg2, bg2, Wg3, bg3, Wo1, bo1, Wo2, bo2, out);
}